// Round 5
// baseline (938.323 us; speedup 1.0000x reference)
//
#include <hip/hip_runtime.h>

// LSTM: B=2048, T=512, D=1, H=50, OUT=3, fp32.
// R1-R4 forensics: any mapping holding 200 resident weight floats/lane gets
// VGPR_Count pinned at 112 by the allocator (4-waves/EU occupancy target it
// refuses to drop) -> ~300 phantom moves/step -> 570-600us regardless of
// source-level heroics. Fix: K-SPLIT. Two waves per batch element, wave w
// owns k in [25w, 25w+25): 100 resident weights/lane fits UNDER the 112
// ceiling. Useful FMA/readlane count unchanged; adds one LDS float4
// exchange + one barrier per step (double-buffered by t parity).
// Block = 128 threads (2 waves) = 1 batch element; grid = 2048 blocks
// = 16 waves/CU = 4 waves/SIMD.

#define BB   2048
#define TT   512
#define HH   50
#define KS   25     // k-range per wave

__device__ __forceinline__ float readlane_f(float v, int lane) {
    union { float f; int i; } u;
    u.f = v;
    u.i = __builtin_amdgcn_readlane(u.i, lane);
    return u.f;
}

__device__ __forceinline__ float fast_sigmoid(float x) {
    float e = __builtin_amdgcn_exp2f(-1.4426950408889634f * x);
    return __builtin_amdgcn_rcpf(1.0f + e);
}

__device__ __forceinline__ float fast_tanh(float x) {
    float e = __builtin_amdgcn_exp2f(-2.8853900817779268f * x);  // e^{-2x}
    return __builtin_amdgcn_rcpf(1.0f + e) * 2.0f - 1.0f;
}

// Apply macro M to i = 0..24
#define REPK25(M) \
  M(0)  M(1)  M(2)  M(3)  M(4)  M(5)  M(6)  M(7)  M(8)  M(9)  \
  M(10) M(11) M(12) M(13) M(14) M(15) M(16) M(17) M(18) M(19) \
  M(20) M(21) M(22) M(23) M(24)

__global__ __attribute__((amdgpu_flat_work_group_size(128, 128)))
void lstm_scan_kernel(const float* __restrict__ x,
                      const float* __restrict__ W_ih,
                      const float* __restrict__ W_hh,
                      const float* __restrict__ b_ih,
                      const float* __restrict__ b_hh,
                      const float* __restrict__ fc_w,
                      const float* __restrict__ fc_b,
                      float* __restrict__ out) {
    __shared__ float  xs[TT];            // this block's x row (2 KB)
    __shared__ float4 part[2][2][64];    // [t parity][wave][lane] partials (4 KB)

    const int tid  = threadIdx.x;
    const int wave = tid >> 6;           // 0 or 1
    const int lane = tid & 63;
    const int b    = blockIdx.x;

    // Stage x row (coalesced: 512 floats / 128 threads)
    #pragma unroll
    for (int i = 0; i < 4; ++i) {
        int idx = i * 128 + tid;
        xs[idx] = x[b * TT + idx];
    }
    __syncthreads();

    const int j  = (lane < HH) ? lane : (HH - 1);  // clamp idle lanes
    const int kb = wave * KS;                      // this wave's k base

    // 100 named weight scalars: w{g}_{i} = W_hh[(g*H + j)*H + kb + i]
#define WDECL(i) \
    float w0_##i = W_hh[(0 * HH + j) * HH + kb + (i)]; \
    float w1_##i = W_hh[(1 * HH + j) * HH + kb + (i)]; \
    float w2_##i = W_hh[(2 * HH + j) * HH + kb + (i)]; \
    float w3_##i = W_hh[(3 * HH + j) * HH + kb + (i)];
    REPK25(WDECL)
#undef WDECL

    // Input projection + biases only contribute once: wave 0 carries them.
    const float m   = (wave == 0) ? 1.0f : 0.0f;
    const float wi0 = m * W_ih[0 * HH + j];
    const float wi1 = m * W_ih[1 * HH + j];
    const float wi2 = m * W_ih[2 * HH + j];
    const float wi3 = m * W_ih[3 * HH + j];
    const float bs0 = m * (b_ih[0 * HH + j] + b_hh[0 * HH + j]);
    const float bs1 = m * (b_ih[1 * HH + j] + b_hh[1 * HH + j]);
    const float bs2 = m * (b_ih[2 * HH + j] + b_hh[2 * HH + j]);
    const float bs3 = m * (b_ih[3 * HH + j] + b_hh[3 * HH + j]);

    float h = 0.0f, c = 0.0f;

    #pragma unroll 1
    for (int t = 0; t < TT; ++t) {
        const float xv = xs[t];                    // uniform LDS broadcast
        float ai = fmaf(xv, wi0, bs0);
        float af = fmaf(xv, wi1, bs1);
        float ag = fmaf(xv, wi2, bs2);
        float ao = fmaf(xv, wi3, bs3);
#define KSTEP(i) { \
        const float hk = readlane_f(h, kb + (i)); \
        ai = fmaf(hk, w0_##i, ai); \
        af = fmaf(hk, w1_##i, af); \
        ag = fmaf(hk, w2_##i, ag); \
        ao = fmaf(hk, w3_##i, ao); }
        REPK25(KSTEP)
#undef KSTEP
        // Cross-wave partial-sum exchange (double-buffered by t parity;
        // single barrier per step is race-free: slot p written at t is read
        // before the t+1 barrier, and rewritten only after it, at t+2).
        part[t & 1][wave][lane] = make_float4(ai, af, ag, ao);
        __syncthreads();
        const float4 o4 = part[t & 1][1 - wave][lane];
        ai += o4.x; af += o4.y; ag += o4.z; ao += o4.w;

        const float ig = fast_sigmoid(ai);
        const float fg = fast_sigmoid(af);
        const float gg = fast_tanh(ag);
        const float og = fast_sigmoid(ao);
        c = fmaf(fg, c, ig * gg);          // both waves compute identical c,h
        h = og * fast_tanh(c);
    }

    // Epilogue (wave 0 only): out[b][o] = sum_j h_j * fc_w[o][j] + fc_b[o]
    if (wave == 0) {
        const float hv = (lane < HH) ? h : 0.0f;
        float r0 = hv * fc_w[0 * HH + j];
        float r1 = hv * fc_w[1 * HH + j];
        float r2 = hv * fc_w[2 * HH + j];
        #pragma unroll
        for (int off = 32; off > 0; off >>= 1) {
            r0 += __shfl_down(r0, off, 64);
            r1 += __shfl_down(r1, off, 64);
            r2 += __shfl_down(r2, off, 64);
        }
        if (lane == 0) {
            out[b * 3 + 0] = r0 + fc_b[0];
            out[b * 3 + 1] = r1 + fc_b[1];
            out[b * 3 + 2] = r2 + fc_b[2];
        }
    }
}

extern "C" void kernel_launch(void* const* d_in, const int* in_sizes, int n_in,
                              void* d_out, int out_size, void* d_ws, size_t ws_size,
                              hipStream_t stream) {
    const float* x    = (const float*)d_in[0];
    const float* W_ih = (const float*)d_in[1];
    const float* W_hh = (const float*)d_in[2];
    const float* b_ih = (const float*)d_in[3];
    const float* b_hh = (const float*)d_in[4];
    const float* fc_w = (const float*)d_in[5];
    const float* fc_b = (const float*)d_in[6];
    float* out = (float*)d_out;

    dim3 grid(BB);       // one block (2 waves) per batch element
    dim3 block(128);
    lstm_scan_kernel<<<grid, block, 0, stream>>>(x, W_ih, W_hh, b_ih, b_hh,
                                                 fc_w, fc_b, out);
}

// Round 6
// 601.483 us; speedup vs baseline: 1.5600x; 1.5600x over previous
//
#include <hip/hip_runtime.h>

// LSTM: B=2048, T=512, D=1, H=50, OUT=3, fp32.
// One wave64 per block, one batch element per wave (2048 waves = 2/SIMD).
// Lane j owns hidden unit j; its 200 recurrent weights are loaded once and
// PINNED with empty inline-asm (asm("" : "+v")) so LLVM cannot rematerialize
// them by re-loading from L1/L2 inside the 512-step loop. R1-R5 forensics:
// VALUBusy ~90% with ~2x the useful instruction stream, FETCH_SIZE flat,
// VGPR_Count stuck at compiler-chosen values (112/72) regardless of source
// tricks -> remat re-loads (L1/L2-hit, invisible in FETCH_SIZE) are the
// phantom work. Pinning forces true residency; block=64 + waves_per_eu(1,2)
// gives the allocator a 256-arch-VGPR budget for the ~235-float working set.
// h_k broadcast via v_readlane -> SGPR fmac operand; no barriers in the scan.

#define BB   2048
#define TT   512
#define HH   50

__device__ __forceinline__ float readlane_f(float v, int lane) {
    union { float f; int i; } u;
    u.f = v;
    u.i = __builtin_amdgcn_readlane(u.i, lane);
    return u.f;
}

__device__ __forceinline__ float fast_sigmoid(float x) {
    float e = __builtin_amdgcn_exp2f(-1.4426950408889634f * x);
    return __builtin_amdgcn_rcpf(1.0f + e);
}

__device__ __forceinline__ float fast_tanh(float x) {
    float e = __builtin_amdgcn_exp2f(-2.8853900817779268f * x);  // e^{-2x}
    return __builtin_amdgcn_rcpf(1.0f + e) * 2.0f - 1.0f;
}

// Opaque register pin: kills rematerialization of the load that produced v.
#define PIN(v) asm("" : "+v"(v))

// Apply macro M to k = 0..49
#define REPK(M) \
  M(0)  M(1)  M(2)  M(3)  M(4)  M(5)  M(6)  M(7)  M(8)  M(9)  \
  M(10) M(11) M(12) M(13) M(14) M(15) M(16) M(17) M(18) M(19) \
  M(20) M(21) M(22) M(23) M(24) M(25) M(26) M(27) M(28) M(29) \
  M(30) M(31) M(32) M(33) M(34) M(35) M(36) M(37) M(38) M(39) \
  M(40) M(41) M(42) M(43) M(44) M(45) M(46) M(47) M(48) M(49)

__global__ __launch_bounds__(64)
__attribute__((amdgpu_waves_per_eu(1, 2)))
void lstm_scan_kernel(const float* __restrict__ x,
                      const float* __restrict__ W_ih,
                      const float* __restrict__ W_hh,
                      const float* __restrict__ b_ih,
                      const float* __restrict__ b_hh,
                      const float* __restrict__ fc_w,
                      const float* __restrict__ fc_b,
                      float* __restrict__ out) {
    __shared__ float xs[TT];     // this wave's x row (2 KB)

    const int lane = threadIdx.x;    // block == one wave
    const int b    = blockIdx.x;

    // Stage x row with float4 loads (2 x 1KB coalesced instructions)
    const float4* xg  = (const float4*)(x + b * TT);
    float4*       xs4 = (float4*)xs;
    xs4[lane]      = xg[lane];
    xs4[lane + 64] = xg[lane + 64];
    __syncthreads();

    const int j = (lane < HH) ? lane : (HH - 1);   // clamp idle lanes

    // 200 weight scalars, loaded once and pinned non-rematerializable.
#define WDECL(k) \
    float w0_##k = W_hh[(0 * HH + j) * HH + (k)]; \
    float w1_##k = W_hh[(1 * HH + j) * HH + (k)]; \
    float w2_##k = W_hh[(2 * HH + j) * HH + (k)]; \
    float w3_##k = W_hh[(3 * HH + j) * HH + (k)];
    REPK(WDECL)
#undef WDECL
#define WPIN(k) \
    PIN(w0_##k); PIN(w1_##k); PIN(w2_##k); PIN(w3_##k);
    REPK(WPIN)
#undef WPIN

    float wi0 = W_ih[0 * HH + j];
    float wi1 = W_ih[1 * HH + j];
    float wi2 = W_ih[2 * HH + j];
    float wi3 = W_ih[3 * HH + j];
    float bs0 = b_ih[0 * HH + j] + b_hh[0 * HH + j];
    float bs1 = b_ih[1 * HH + j] + b_hh[1 * HH + j];
    float bs2 = b_ih[2 * HH + j] + b_hh[2 * HH + j];
    float bs3 = b_ih[3 * HH + j] + b_hh[3 * HH + j];
    PIN(wi0); PIN(wi1); PIN(wi2); PIN(wi3);
    PIN(bs0); PIN(bs1); PIN(bs2); PIN(bs3);

    float h = 0.0f, c = 0.0f;

    float xc = xs[0];                    // software-pipelined x read
    #pragma unroll 1
    for (int t = 0; t < TT; ++t) {
        const float xn = xs[(t + 1) & (TT - 1)];   // prefetch next step
        float ai = fmaf(xc, wi0, bs0);
        float af = fmaf(xc, wi1, bs1);
        float ag = fmaf(xc, wi2, bs2);
        float ao = fmaf(xc, wi3, bs3);
#define KSTEP(k) { \
        const float hk = readlane_f(h, k); \
        ai = fmaf(hk, w0_##k, ai); \
        af = fmaf(hk, w1_##k, af); \
        ag = fmaf(hk, w2_##k, ag); \
        ao = fmaf(hk, w3_##k, ao); }
        REPK(KSTEP)
#undef KSTEP
        const float ig = fast_sigmoid(ai);
        const float fg = fast_sigmoid(af);
        const float gg = fast_tanh(ag);
        const float og = fast_sigmoid(ao);
        c = fmaf(fg, c, ig * gg);
        h = og * fast_tanh(c);
        xc = xn;
    }

    // Epilogue: out[b][o] = sum_j h_j * fc_w[o][j] + fc_b[o]
    const float hv = (lane < HH) ? h : 0.0f;
    float r0 = hv * fc_w[0 * HH + j];
    float r1 = hv * fc_w[1 * HH + j];
    float r2 = hv * fc_w[2 * HH + j];
    #pragma unroll
    for (int off = 32; off > 0; off >>= 1) {
        r0 += __shfl_down(r0, off, 64);
        r1 += __shfl_down(r1, off, 64);
        r2 += __shfl_down(r2, off, 64);
    }
    if (lane == 0) {
        out[b * 3 + 0] = r0 + fc_b[0];
        out[b * 3 + 1] = r1 + fc_b[1];
        out[b * 3 + 2] = r2 + fc_b[2];
    }
}

extern "C" void kernel_launch(void* const* d_in, const int* in_sizes, int n_in,
                              void* d_out, int out_size, void* d_ws, size_t ws_size,
                              hipStream_t stream) {
    const float* x    = (const float*)d_in[0];
    const float* W_ih = (const float*)d_in[1];
    const float* W_hh = (const float*)d_in[2];
    const float* b_ih = (const float*)d_in[3];
    const float* b_hh = (const float*)d_in[4];
    const float* fc_w = (const float*)d_in[5];
    const float* fc_b = (const float*)d_in[6];
    float* out = (float*)d_out;

    dim3 grid(BB);       // one wave64 block per batch element
    dim3 block(64);
    lstm_scan_kernel<<<grid, block, 0, stream>>>(x, W_ih, W_hh, b_ih, b_hh,
                                                 fc_w, fc_b, out);
}